// Round 8
// baseline (708.240 us; speedup 1.0000x reference)
//
#include <hip/hip_runtime.h>
#include <stdint.h>

// Problem constants: x[16,64,256,256] fp32, W[1024,1024] fp32, P=4.
// GEMM view: C[m,n] = sum_k A[m,k] * W[n,k]
//   m = b*4096 + hp*64 + wp   (Hp=Wp=64)
//   k = c*16 + ph*4 + pw
//
// Round-8: r7's zero-sync decomposition (wave owns 32 rows x 128 cols,
// A direct from x with zero redundancy, B from pre-packed bf16 table Wp)
// + PINNED software pipeline. r5 (barriers) and r7 (no barriers) both ran
// ~1300-1500 cyc/wave-iter with all pipes <20% busy: loads were not
// overlapping iterations -- each body paid full memory latency serially.
// Fix (T4/T14): issue-first loads, one counted s_waitcnt vmcnt(12) per
// body (never 0), sched_barrier(0) pins so the compiler can neither sink
// the loads below the MFMAs nor hoist the MFMAs above the wait (rule #18).
// Steady state: every wait targets data issued a full body earlier.
// Cost: B reg ping-pong (+32 VGPR) -> ~180 regs -> 2 waves/SIMD. r6 proved
// occupancy isn't the lever here; pinned ILP is the bet.

typedef float    f32x4  __attribute__((ext_vector_type(4)));
typedef uint32_t u32x4  __attribute__((ext_vector_type(4)));
typedef __bf16   bf16x8 __attribute__((ext_vector_type(8)));

// Truncate two f32 to bf16 and pack into one u32 (lo in low half).
__device__ __forceinline__ uint32_t pack2(float lo, float hi) {
    return __builtin_amdgcn_perm(__builtin_bit_cast(uint32_t, hi),
                                 __builtin_bit_cast(uint32_t, lo),
                                 0x07060302u);
}

// ---- W prep: W[n][k] fp32 -> Wp granule[kq][n] = 8 bf16 {k=kq*8..kq*8+7} ----
// 128k granules (kq 0..127, n 0..1023) = 2 MB, L2-resident.
__global__ __launch_bounds__(256)
void wprep_kernel(const float* __restrict__ Wm, u32x4* __restrict__ Wp) {
    const int t  = blockIdx.x * 256 + threadIdx.x;   // 0..131071
    if (t >= 128 * 1024) return;
    const int n  = t & 1023;                          // write-coalesced in n
    const int kq = t >> 10;                           // 0..127
    const float* src = Wm + (size_t)n * 1024 + (size_t)kq * 8;
    f32x4 lo = *(const f32x4*)(src);
    f32x4 hi = *(const f32x4*)(src + 4);
    Wp[(size_t)kq * 1024 + n] = (u32x4){ pack2(lo.x, lo.y), pack2(lo.z, lo.w),
                                         pack2(hi.x, hi.y), pack2(hi.z, hi.w) };
}

__global__ __launch_bounds__(256, 2)
void patchmix_kernel(const float* __restrict__ x,
                     const u32x4* __restrict__ Wp,
                     float* __restrict__ y) {
    // ---- XCD-aware block swizzle (T1): contiguous M-chunk per XCD, N fastest.
    const int bx  = blockIdx.x;
    const int xcd = bx & 7;
    const int jj  = bx >> 3;       // 0..511 within this XCD
    const int nt  = jj & 7;        // N-tile fastest -> A-strip L2 reuse
    const int mt  = xcd * 64 + (jj >> 3);   // 0..511
    const int bb  = mt >> 5;       // batch 0..15
    const int hp0 = (mt & 31) << 1;// first of 2 hp rows
    const int n0  = nt << 7;

    const int t    = threadIdx.x;
    const int lane = t & 63;
    const int wave = t >> 6;       // wave owns rows [wave*32, wave*32+32)

    const int kg  = lane >> 4;     // k-group 0..3
    const int lr  = lane & 15;

    // ---- A fragment geometry (direct from x, zero redundancy; r7 verbatim).
    // af[i]: lane holds A[m_local = wave*32 + i*16 + lr][k = kg*8 + j2].
    const float* aBase = x + (size_t)bb * 4194304
                       + (size_t)(kg >> 1) * 65536
                       + ((size_t)(hp0 + (wave >> 1)) * 4 + 2 * (kg & 1)) * 256
                       + (size_t)((wave & 1) * 32 + lr) * 4;

    // ---- B fragment pointer: granule (it*4+kg)*1024 + (n0 + j*16 + lr) ----
    const u32x4* bFrag = Wp + (size_t)kg * 1024 + (size_t)(n0 + lr);

    f32x4 aA[2][2], aB[2][2];   // A ping-pong, 2 iterations deep (fp32)
    u32x4 bA[8],    bB[8];      // B ping-pong, 1 iteration deep (bf16 granules)

    auto loadA = [&](int it, f32x4 (&aU)[2][2]) {
        const float* a0 = aBase + (size_t)it * 131072;   // 2 channels/iter
        #pragma unroll
        for (int i = 0; i < 2; ++i) {
            aU[i][0] = *(const f32x4*)(a0 + i * 64);
            aU[i][1] = *(const f32x4*)(a0 + i * 64 + 256);
        }
    };
    auto loadB = [&](int it, u32x4 (&bU)[8]) {
        const u32x4* bi = bFrag + (size_t)it * 4096;
        #pragma unroll
        for (int j = 0; j < 8; ++j)
            bU[j] = bi[j * 16];
    };

    f32x4 acc[2][8];
    #pragma unroll
    for (int i = 0; i < 2; ++i)
        #pragma unroll
        for (int j = 0; j < 8; ++j)
            acc[i][j] = (f32x4){0.f, 0.f, 0.f, 0.f};

    // ---- prologue: A(0)->aA, A(1)->aB, B(0)->bA ----
    loadA(0, aA);
    loadB(0, bA);
    loadA(1, aB);

    // body(it): consumes A(it) from aU and B(it) from bU;
    //           refills aU with A(it+2), bV with B(it+1).
    auto body = [&](int it, f32x4 (&aU)[2][2], u32x4 (&bU)[8], u32x4 (&bV)[8]) {
        // 1. pack A(it) -> bf16 fragments. Its loads are 2 bodies old;
        //    compiler emits counted vmcnt here (12 newer loads outstanding).
        bf16x8 af[2];
        #pragma unroll
        for (int i = 0; i < 2; ++i) {
            u32x4 ap = (u32x4){ pack2(aU[i][0].x, aU[i][0].y), pack2(aU[i][0].z, aU[i][0].w),
                                pack2(aU[i][1].x, aU[i][1].y), pack2(aU[i][1].z, aU[i][1].w) };
            af[i] = __builtin_bit_cast(bf16x8, ap);
        }
        // 2. issue next loads (WAR on aU is safe: pack's reads precede issue)
        const int itA = (it + 2 < 32) ? (it + 2) : 31;
        const int itB = (it + 1 < 32) ? (it + 1) : 31;
        loadA(itA, aU);
        loadB(itB, bV);
        // 3. pin: loads must be issued above this point
        __builtin_amdgcn_sched_barrier(0);
        // 4. counted wait: drains B(it)+A(it+1) (issued last body); the 12
        //    just-issued loads stay in flight across the MFMA block.
        asm volatile("s_waitcnt vmcnt(12)" ::: "memory");
        // 5. pin: MFMAs must not hoist above the wait (rule #18)
        __builtin_amdgcn_sched_barrier(0);
        __builtin_amdgcn_s_setprio(1);
        #pragma unroll
        for (int j = 0; j < 8; ++j) {
            bf16x8 bfj = __builtin_bit_cast(bf16x8, bU[j]);
            acc[0][j] = __builtin_amdgcn_mfma_f32_16x16x32_bf16(af[0], bfj, acc[0][j], 0, 0, 0);
            acc[1][j] = __builtin_amdgcn_mfma_f32_16x16x32_bf16(af[1], bfj, acc[1][j], 0, 0, 0);
        }
        __builtin_amdgcn_s_setprio(0);
    };

    #pragma unroll 1
    for (int it2 = 0; it2 < 16; ++it2) {
        body(2 * it2,     aA, bA, bB);
        body(2 * it2 + 1, aB, bB, bA);
    }

    // ---- epilogue: fold back to y[b][c][h][w] (r7 verbatim) ----
    // D layout (m89): col n = lane&15, row m16 = (lane>>4)*4 + reg
    // m_local = wave*32 + i*16 + kg*4 + r -> hpL = wave>>1,
    // wp = (wave&1)*32 + i*16 + kg*4 + r
    float* yb = y + (size_t)bb * (64 * 256 * 256)
                  + ((size_t)(hp0 + (wave >> 1)) * 4) * 256;
    #pragma unroll
    for (int j = 0; j < 8; ++j) {
        const int ng = n0 + j * 16 + lr;   // output channel-dim index e
        const int cc = ng >> 4;
        const int ph = (ng >> 2) & 3;
        const int pw = ng & 3;
        float* ybase = yb + ((size_t)cc * 256 + ph) * 256 + pw;
        #pragma unroll
        for (int i = 0; i < 2; ++i) {
            const int wpB = (wave & 1) * 32 + i * 16 + kg * 4;
            #pragma unroll
            for (int r = 0; r < 4; ++r)
                ybase[(size_t)(wpB + r) * 4] = acc[i][j][r];
        }
    }
}

extern "C" void kernel_launch(void* const* d_in, const int* in_sizes, int n_in,
                              void* d_out, int out_size, void* d_ws, size_t ws_size,
                              hipStream_t stream) {
    (void)in_sizes; (void)n_in; (void)out_size; (void)ws_size;
    const float* x  = (const float*)d_in[0];
    const float* Wm = (const float*)d_in[1];
    float* y = (float*)d_out;
    u32x4* Wp = (u32x4*)d_ws;   // needs 2 MB; harness workspace is larger
    wprep_kernel<<<dim3(512), dim3(256), 0, stream>>>(Wm, Wp);
    // 512 M-tiles x 8 N-tiles
    patchmix_kernel<<<dim3(4096), dim3(256), 0, stream>>>(x, Wp, y);
}